// Round 11
// baseline (121.306 us; speedup 1.0000x reference)
//
#include <hip/hip_runtime.h>

constexpr int TPB   = 256;
constexpr int ITEMS = 32;
constexpr int TILE  = TPB * ITEMS;   // 8192 elements per block
constexpr int GRID  = 977;           // 977*8192 = 8,003,584 >= 8,000,000
constexpr unsigned MAGIC = 0xC0DE600Du;   // != 0xAAAAAAAA ws-poison, != 0
constexpr int PAD   = 33;            // LDS chunk stride: bank=(chunk+j)%32 -> 2-way, free

// Clamp monoid: f(x) = min(max(x + A, B), C). compose(l, r) (l applied first):
//   A = Al + Ar;  B = max(Bl + Ar, Br);  C = min(max(Cl + Ar, Br), Cr)
// Identity (0,-INF,+INF). Saturated (constant) <=> B >= C, value C.
// Affine monoid: f(x) = P*x + Q. compose(l, r): P = Pl*Pr; Q = Pr*Ql + Qr.
//
// R11 = R10 (gate-free speculative throughput path) + coalesced input staging:
// global float4 loads at idx=u*TPB+tid (16 lines/instr, not 64) -> stride-33
// padded LDS -> per-thread contiguous register chunk. R8's 64-way-conflict
// disaster avoided by the +1 chunk pad. Stores remain direct (non-blocking).
//
// Gate-free throughput path (R10):
//  * phase-A publish and (P,Q) publish: exact (to <1e-35), no waits.
//  * saturated thread (eB>=eC): S_thread = eC independent of block-start S;
//    benched data saturates every thread except tid 0.
//  * B-start influence on thread t damped by k^(32t) <= 2e-10 for t>=1.
//  => threads >= 2 compute AND store with zero cross-block waits.
//  * lane 0 alone consumes both 1-hop gates, recomputes elements [0,64).
//  * runtime fallback (unsat thread tid>0, or k outside (0,0.7)): exact path.
// Deadlock-freedom: waits target only lower blockIdx (ascending dispatch,
// publishes unconditional and gate-free). Fence-free sync: relaxed agent-scope
// atomics; producer orders data->flag with s_waitcnt vmcnt(0).

#define AT_LOAD(p)    __hip_atomic_load((p), __ATOMIC_RELAXED, __HIP_MEMORY_SCOPE_AGENT)
#define AT_STORE(p,v) __hip_atomic_store((p), (v), __ATOMIC_RELAXED, __HIP_MEMORY_SCOPE_AGENT)

__global__ __launch_bounds__(TPB, 4)
void awbm_kernel(const float* __restrict__ x,
                 const float* __restrict__ pBFI,
                 const float* __restrict__ pK,
                 const float* __restrict__ pSmax,
                 float* __restrict__ out,
                 float* __restrict__ ws,
                 int T)
{
    __shared__ float lds_t[TPB * PAD];   // 8448 floats = 33792 B (4 blocks/CU fits 160K)
    __shared__ float sm3[12];    // phase-A wave aggregates (3 x 4 waves)
    __shared__ float sm2[8];     // phase-C wave aggregates (2 x 4 waves)
    __shared__ float bc[2];      // fallback broadcast: S / B at block start

    const int tid  = threadIdx.x;
    const int lane = tid & 63;
    const int wv   = tid >> 6;
    const int b    = blockIdx.x;
    const int gbase = b * TILE;
    const int toff  = tid * ITEMS;
    const bool full = (gbase + toff) < T;      // all-or-nothing (tail = 144*32 exactly)

    // ---- stage x -> LDS (COALESCED), padded transpose ----
    {
        const float4* x4 = (const float4*)x + ((long)gbase >> 1);
        const int rem = T - gbase;             // block's valid elements (even)
        float4 v[16];
#pragma unroll
        for (int u = 0; u < 16; ++u) {
            int idx = u * TPB + tid;           // lane-contiguous float4 index
            v[u] = (2 * idx < rem) ? x4[idx] : make_float4(0.f, 0.f, 0.f, 0.f);
        }
#pragma unroll
        for (int u = 0; u < 16; ++u) {
            int idx = u * TPB + tid;
            int e   = 2 * idx;                 // even => e,e+1 share a 32-chunk
            int a   = (e >> 5) * PAD + (e & 31);
            lds_t[a]     = v[u].x - v[u].y;
            lds_t[a + 1] = v[u].z - v[u].w;
        }
    }
    __syncthreads();   // B0

    // ---- per-thread contiguous chunk -> registers (2-way bank, free) ----
    float d[ITEMS];
    if (full) {
        const int base = tid * PAD;
#pragma unroll
        for (int j = 0; j < ITEMS; ++j) d[j] = lds_t[base + j];
    }

    float*    scrA = ws;
    float*    scrB = ws + GRID;
    float*    scrC = ws + 2 * GRID;
    float*    scrP = ws + 3 * GRID;
    float*    scrQ = ws + 4 * GRID;
    unsigned* f1   = (unsigned*)(ws + 5 * GRID);
    unsigned* f2   = (unsigned*)(ws + 6 * GRID);

    const float bfi  = pBFI[0];
    const float k    = pK[0];
    const float smax = pSmax[0];
    const float omb  = 1.0f - bfi;
    const float omk  = 1.0f - k;
    const float INF  = __builtin_inff();

    // ---- Phase A: per-thread clamp fold (identity if empty) ----
    float rA = 0.f, rB = -INF, rC = INF;
    if (full) {
#pragma unroll
        for (int j = 0; j < ITEMS; ++j) {
            float dd = d[j];
            rA += dd;
            rB = fmaxf(rB + dd, 0.f);
            rC = fminf(fmaxf(rC + dd, 0.f), smax);
        }
    }
#pragma unroll
    for (int s = 1; s < 64; s <<= 1) {
        float pA = __shfl_up(rA, s, 64), pB = __shfl_up(rB, s, 64), pC = __shfl_up(rC, s, 64);
        if (lane >= s) {
            float nA = pA + rA, nB = fmaxf(pB + rA, rB), nC = fminf(fmaxf(pC + rA, rB), rC);
            rA = nA; rB = nB; rC = nC;
        }
    }
    if (lane == 63) { sm3[wv * 3] = rA; sm3[wv * 3 + 1] = rB; sm3[wv * 3 + 2] = rC; }
    __syncthreads();   // B1
    float wA = 0.f, wB = -INF, wC = INF;       // exclusive cross-wave prefix
    for (int i = 0; i < wv; ++i) {
        float a = sm3[i * 3], bb = sm3[i * 3 + 1], c = sm3[i * 3 + 2];
        float nA = wA + a, nB = fmaxf(wB + a, bb), nC = fminf(fmaxf(wC + a, bb), c);
        wA = nA; wB = nB; wC = nC;
    }
    {   // thread inclusive across block
        float nA = wA + rA, nB = fmaxf(wB + rA, rB), nC = fminf(fmaxf(wC + rA, rB), rC);
        rA = nA; rB = nB; rC = nC;
    }
    if (tid == TPB - 1) {                      // publish1: exact, gate-free
        AT_STORE(&scrA[b], rA); AT_STORE(&scrB[b], rB); AT_STORE(&scrC[b], rC);
        __atomic_signal_fence(__ATOMIC_SEQ_CST);
        __builtin_amdgcn_s_waitcnt(0);
        __atomic_signal_fence(__ATOMIC_SEQ_CST);
        AT_STORE(&f1[b], MAGIC);
    }
    float eA, eB, eC;                          // thread-exclusive prefix map
    {
        float pA = __shfl_up(rA, 1, 64), pB = __shfl_up(rB, 1, 64), pC = __shfl_up(rC, 1, 64);
        eA = (lane == 0) ? wA : pA;
        eB = (lane == 0) ? wB : pB;
        eC = (lane == 0) ? wC : pC;
    }

    // ---- fast/fallback decision (B2) ----
    int bad = (full && tid > 0 && eB < eC) ? 1 : 0;
    int cnt = __syncthreads_count(bad);
    const bool fallback = (cnt != 0) || !(k > 0.0f && k < 0.70f) || (T - gbase < 64);

    if (!fallback) {
        // ================= FAST PATH (gate-free throughput) =================
        float S = fminf(fmaxf(0.5f + eA, eB), eC);   // exact for saturated threads
        float p = 1.f, c = 0.f;
        if (full) {
#pragma unroll
            for (int j = 0; j < ITEMS; ++j) {
                float dd = d[j];
                float S1 = fmaxf(S + dd, 0.f);
                float ex = fmaxf(S1 - smax, 0.f);
                S = S1 - ex;
                float w = c + bfi * ex;
                d[j] = omb * ex + omk * w;
                c = k * w;
                p *= k;
            }
        }
#pragma unroll
        for (int s = 1; s < 64; s <<= 1) {
            float pp = __shfl_up(p, s, 64), pc = __shfl_up(c, s, 64);
            if (lane >= s) {
                float nq = p * pc + c;
                p = pp * p;
                c = nq;
            }
        }
        if (lane == 63) { sm2[wv * 2] = p; sm2[wv * 2 + 1] = c; }
        __syncthreads();   // B3
        float wP = 1.f, wQ = 0.f;
        for (int i = 0; i < wv; ++i) {
            float gp = sm2[i * 2], gq = sm2[i * 2 + 1];
            wQ = gp * wQ + gq;
            wP = wP * gp;
        }
        {
            float nq = p * wQ + c;
            p = wP * p;
            c = nq;
        }
        if (tid == TPB - 1) {                  // publish2: exact to <1e-35, gate-free
            AT_STORE(&scrP[b], p); AT_STORE(&scrQ[b], c);
            __atomic_signal_fence(__ATOMIC_SEQ_CST);
            __builtin_amdgcn_s_waitcnt(0);
            __atomic_signal_fence(__ATOMIC_SEQ_CST);
            AT_STORE(&f2[b], MAGIC);
        }
        float eP, eQ;
        {
            float pp = __shfl_up(p, 1, 64), pc = __shfl_up(c, 1, 64);
            eP = (lane == 0) ? wP : pp;
            eQ = (lane == 0) ? wQ : pc;
        }

        // speculative epilogue + store: threads >= 2, zero waits
        if (full && tid >= 2) {
            float Bst = eP * 1.0f + eQ;        // guess B_blockstart=1; err <= k^64
            float f = omk * Bst;
#pragma unroll
            for (int j = 0; j < ITEMS; ++j) { d[j] += f; f *= k; }
            float4* o4 = (float4*)out + ((long)(gbase + toff) >> 2);
#pragma unroll
            for (int u = 0; u < 8; ++u)
                o4[u] = make_float4(d[4 * u], d[4 * u + 1], d[4 * u + 2], d[4 * u + 3]);
        }

        // lane-0 fix-up: both 1-hop gates + exact serial recompute of [0,64)
        if (tid == 0) {
            float Sst;
            if (b == 0) Sst = 0.5f;
            else {
                float aA = 0.f, aB = -INF, aC = INF;
                int j = b - 1;
                for (;;) {
                    if (j < 0) { Sst = fminf(fmaxf(0.5f + aA, aB), aC); break; }
                    while (AT_LOAD(&f1[j]) != MAGIC) __builtin_amdgcn_s_sleep(1);
                    __atomic_signal_fence(__ATOMIC_ACQUIRE);
                    float Aj = AT_LOAD(&scrA[j]), Bj = AT_LOAD(&scrB[j]), Cj = AT_LOAD(&scrC[j]);
                    float nA = Aj + aA, nB = fmaxf(Bj + aA, aB), nC = fminf(fmaxf(Cj + aA, aB), aC);
                    aA = nA; aB = nB; aC = nC;
                    if (aB >= aC) { Sst = aC; break; }
                    --j;
                }
            }
            float Bcur;
            if (b == 0) Bcur = 1.0f;
            else {
                float accP = 1.f, Bacc = 0.f;
                int j = b - 1;
                for (;;) {
                    if (j < 0) { Bacc += accP * 1.0f; break; }
                    if (accP < 1e-35f) break;
                    while (AT_LOAD(&f2[j]) != MAGIC) __builtin_amdgcn_s_sleep(1);
                    __atomic_signal_fence(__ATOMIC_ACQUIRE);
                    float Pj = AT_LOAD(&scrP[j]), Qj = AT_LOAD(&scrQ[j]);
                    Bacc += accP * Qj;
                    accP *= Pj;
                    --j;
                }
                Bcur = Bacc;
            }
            // exact recompute of elements [gbase, gbase+64)
            const float4* xf = (const float4*)x + ((long)gbase >> 1);
            float Sc = Sst;
#pragma unroll
            for (int base = 0; base < 64; base += 16) {
                float4 vv[8];
#pragma unroll
                for (int u = 0; u < 8; ++u) vv[u] = xf[(base >> 1) + u];
                float o[16];
#pragma unroll
                for (int j = 0; j < 16; ++j) {
                    float dd = (j & 1) ? (vv[j >> 1].z - vv[j >> 1].w)
                                       : (vv[j >> 1].x - vv[j >> 1].y);
                    float S1 = fmaxf(Sc + dd, 0.f);
                    float ex = fmaxf(S1 - smax, 0.f);
                    Sc = S1 - ex;
                    Bcur += bfi * ex;
                    float bf = omk * Bcur;
                    Bcur -= bf;
                    o[j] = omb * ex + bf;
                }
                float4* o4 = (float4*)out + ((long)(gbase + base) >> 2);
#pragma unroll
                for (int u = 0; u < 4; ++u)
                    o4[u] = make_float4(o[4 * u], o[4 * u + 1], o[4 * u + 2], o[4 * u + 3]);
            }
        }
    } else {
        // ================= FALLBACK (exact R9 path) =================
        if (tid == 0) {
            float aA = 0.f, aB = -INF, aC = INF;
            float Sst;
            int j = b - 1;
            for (;;) {
                if (j < 0) { Sst = fminf(fmaxf(0.5f + aA, aB), aC); break; }
                while (AT_LOAD(&f1[j]) != MAGIC) __builtin_amdgcn_s_sleep(1);
                __atomic_signal_fence(__ATOMIC_ACQUIRE);
                float Aj = AT_LOAD(&scrA[j]), Bj = AT_LOAD(&scrB[j]), Cj = AT_LOAD(&scrC[j]);
                float nA = Aj + aA, nB = fmaxf(Bj + aA, aB), nC = fminf(fmaxf(Cj + aA, aB), aC);
                aA = nA; aB = nB; aC = nC;
                if (aB >= aC) { Sst = aC; break; }
                --j;
            }
            bc[0] = Sst;
        }
        __syncthreads();
        float S = fminf(fmaxf(bc[0] + eA, eB), eC);
        float p = 1.f, c = 0.f;
        if (full) {
#pragma unroll
            for (int j = 0; j < ITEMS; ++j) {
                float dd = d[j];
                float S1 = fmaxf(S + dd, 0.f);
                float ex = fmaxf(S1 - smax, 0.f);
                S = S1 - ex;
                float w = c + bfi * ex;
                d[j] = omb * ex + omk * w;
                c = k * w;
                p *= k;
            }
        }
#pragma unroll
        for (int s = 1; s < 64; s <<= 1) {
            float pp = __shfl_up(p, s, 64), pc = __shfl_up(c, s, 64);
            if (lane >= s) {
                float nq = p * pc + c;
                p = pp * p;
                c = nq;
            }
        }
        if (lane == 63) { sm2[wv * 2] = p; sm2[wv * 2 + 1] = c; }
        __syncthreads();
        float wP = 1.f, wQ = 0.f;
        for (int i = 0; i < wv; ++i) {
            float gp = sm2[i * 2], gq = sm2[i * 2 + 1];
            wQ = gp * wQ + gq;
            wP = wP * gp;
        }
        {
            float nq = p * wQ + c;
            p = wP * p;
            c = nq;
        }
        if (tid == TPB - 1) {
            AT_STORE(&scrP[b], p); AT_STORE(&scrQ[b], c);
            __atomic_signal_fence(__ATOMIC_SEQ_CST);
            __builtin_amdgcn_s_waitcnt(0);
            __atomic_signal_fence(__ATOMIC_SEQ_CST);
            AT_STORE(&f2[b], MAGIC);
        }
        float eP, eQ;
        {
            float pp = __shfl_up(p, 1, 64), pc = __shfl_up(c, 1, 64);
            eP = (lane == 0) ? wP : pp;
            eQ = (lane == 0) ? wQ : pc;
        }
        if (tid == 0) {
            float accP = 1.f, Bst = 0.f;
            int j = b - 1;
            for (;;) {
                if (j < 0) { Bst += accP * 1.0f; break; }
                if (accP < 1e-35f) break;
                while (AT_LOAD(&f2[j]) != MAGIC) __builtin_amdgcn_s_sleep(1);
                __atomic_signal_fence(__ATOMIC_ACQUIRE);
                float Pj = AT_LOAD(&scrP[j]), Qj = AT_LOAD(&scrQ[j]);
                Bst  += accP * Qj;
                accP *= Pj;
                --j;
            }
            bc[1] = Bst;
        }
        __syncthreads();
        float Bst = eP * bc[1] + eQ;
        if (full) {
            float f = omk * Bst;
#pragma unroll
            for (int j = 0; j < ITEMS; ++j) { d[j] += f; f *= k; }
            float4* o4 = (float4*)out + ((long)(gbase + toff) >> 2);
#pragma unroll
            for (int u = 0; u < 8; ++u)
                o4[u] = make_float4(d[4 * u], d[4 * u + 1], d[4 * u + 2], d[4 * u + 3]);
        }
    }
}

extern "C" void kernel_launch(void* const* d_in, const int* in_sizes, int n_in,
                              void* d_out, int out_size, void* d_ws, size_t ws_size,
                              hipStream_t stream) {
    const float* x    = (const float*)d_in[0];
    const float* BFI  = (const float*)d_in[1];
    const float* K    = (const float*)d_in[2];
    const float* Smax = (const float*)d_in[3];
    float* out = (float*)d_out;
    float* ws  = (float*)d_ws;   // ~27.4 KB; 0xAA poison = "not ready" for flags
    int T = out_size;            // 8,000,000

    awbm_kernel<<<dim3(GRID), dim3(TPB), 0, stream>>>(x, BFI, K, Smax, out, ws, T);
}

// Round 12
// 115.814 us; speedup vs baseline: 1.0474x; 1.0474x over previous
//
#include <hip/hip_runtime.h>

constexpr int TPB   = 256;
constexpr int ITEMS = 32;
constexpr int TILE  = TPB * ITEMS;   // 8192 elements per block
constexpr int GRID  = 977;           // 977*8192 = 8,003,584 >= 8,000,000
constexpr unsigned MAGIC = 0xC0DE600Du;   // != 0xAAAAAAAA ws-poison, != 0

// Clamp monoid: f(x) = min(max(x + A, B), C). compose(l, r) (l applied first):
//   A = Al + Ar;  B = max(Bl + Ar, Br);  C = min(max(Cl + Ar, Br), Cr)
// Identity (0,-INF,+INF). Saturated (constant) <=> B >= C, value C.
// Affine monoid: f(x) = P*x + Q. compose(l, r): P = Pl*Pr; Q = Pr*Ql + Qr.
//
// R12 = R10 reverted verbatim (best measured: 114.8 us wall). R11's coalesced
// staging via padded LDS transpose REGRESSED (121.3): the strided 256B/lane
// direct loads are not transaction-bound; the LDS round-trip + extra barrier
// and staging drain cost more than they save.
//
// Gate-free speculative throughput path:
//  * phase-A publish: always exact, gate-free.
//  * (P,Q) publish: exact to <1e-35 with speculative c0 (damped by k^(32*255)).
//  * saturated thread (eB>=eC): S_thread = eC independent of block-start S.
//    Benched random-walk data saturates every thread except tid 0.
//  * B-start influence on thread t damped by k^(32t) (<=2e-10 for t>=1, k<=0.7).
//  => threads >= 2 compute AND STORE with zero cross-block waits; no block
//     ever waits on another block's gate => no chaining anywhere.
//  * lane 0 alone consumes both 1-hop gates and serially recomputes/stores
//    elements [0,64) of the block (threads 0,1: the only undamped errors).
//  * runtime fallback (any unsat thread with tid>0, or k outside (0,0.7)):
//    exact R9-style broadcast path.
// Deadlock-freedom: waits target only lower blockIdx; publishes are
// unconditional and precede all waits; dispatch order ascending and 977
// blocks at 4/CU are fully co-resident.
// Fence-free sync: scratch = relaxed agent-scope atomics (coherence point,
// never stale); producer orders data->flag with s_waitcnt vmcnt(0).

#define AT_LOAD(p)    __hip_atomic_load((p), __ATOMIC_RELAXED, __HIP_MEMORY_SCOPE_AGENT)
#define AT_STORE(p,v) __hip_atomic_store((p), (v), __ATOMIC_RELAXED, __HIP_MEMORY_SCOPE_AGENT)

__global__ __launch_bounds__(TPB, 4)
void awbm_kernel(const float* __restrict__ x,
                 const float* __restrict__ pBFI,
                 const float* __restrict__ pK,
                 const float* __restrict__ pSmax,
                 float* __restrict__ out,
                 float* __restrict__ ws,
                 int T)
{
    __shared__ float sm3[12];    // phase-A wave aggregates (3 x 4 waves)
    __shared__ float sm2[8];     // phase-C wave aggregates (2 x 4 waves)
    __shared__ float bc[2];      // fallback broadcast: S / B at block start

    const int tid  = threadIdx.x;
    const int lane = tid & 63;
    const int wv   = tid >> 6;
    const int b    = blockIdx.x;
    const int gbase = b * TILE;
    const int toff  = tid * ITEMS;
    const bool full = (gbase + toff) < T;      // all-or-nothing (divisibility)

    // ---- stage x -> registers FIRST: 16 independent dwordx4 loads ----
    float d[ITEMS];
    if (full) {
        const float4* x4 = (const float4*)x + ((long)(gbase + toff) >> 1);
        float4 v[16];
#pragma unroll
        for (int u = 0; u < 16; ++u) v[u] = x4[u];
#pragma unroll
        for (int u = 0; u < 16; ++u) {
            d[2 * u]     = v[u].x - v[u].y;
            d[2 * u + 1] = v[u].z - v[u].w;
        }
    }

    float*    scrA = ws;
    float*    scrB = ws + GRID;
    float*    scrC = ws + 2 * GRID;
    float*    scrP = ws + 3 * GRID;
    float*    scrQ = ws + 4 * GRID;
    unsigned* f1   = (unsigned*)(ws + 5 * GRID);
    unsigned* f2   = (unsigned*)(ws + 6 * GRID);

    const float bfi  = pBFI[0];
    const float k    = pK[0];
    const float smax = pSmax[0];
    const float omb  = 1.0f - bfi;
    const float omk  = 1.0f - k;
    const float INF  = __builtin_inff();

    // ---- Phase A: per-thread clamp fold (identity if empty) ----
    float rA = 0.f, rB = -INF, rC = INF;
    if (full) {
#pragma unroll
        for (int j = 0; j < ITEMS; ++j) {
            float dd = d[j];
            rA += dd;
            rB = fmaxf(rB + dd, 0.f);
            rC = fminf(fmaxf(rC + dd, 0.f), smax);
        }
    }
#pragma unroll
    for (int s = 1; s < 64; s <<= 1) {
        float pA = __shfl_up(rA, s, 64), pB = __shfl_up(rB, s, 64), pC = __shfl_up(rC, s, 64);
        if (lane >= s) {
            float nA = pA + rA, nB = fmaxf(pB + rA, rB), nC = fminf(fmaxf(pC + rA, rB), rC);
            rA = nA; rB = nB; rC = nC;
        }
    }
    if (lane == 63) { sm3[wv * 3] = rA; sm3[wv * 3 + 1] = rB; sm3[wv * 3 + 2] = rC; }
    __syncthreads();   // B1
    float wA = 0.f, wB = -INF, wC = INF;       // exclusive cross-wave prefix
    for (int i = 0; i < wv; ++i) {
        float a = sm3[i * 3], bb = sm3[i * 3 + 1], c = sm3[i * 3 + 2];
        float nA = wA + a, nB = fmaxf(wB + a, bb), nC = fminf(fmaxf(wC + a, bb), c);
        wA = nA; wB = nB; wC = nC;
    }
    {   // thread inclusive across block
        float nA = wA + rA, nB = fmaxf(wB + rA, rB), nC = fminf(fmaxf(wC + rA, rB), rC);
        rA = nA; rB = nB; rC = nC;
    }
    if (tid == TPB - 1) {                      // publish1: exact, gate-free
        AT_STORE(&scrA[b], rA); AT_STORE(&scrB[b], rB); AT_STORE(&scrC[b], rC);
        __atomic_signal_fence(__ATOMIC_SEQ_CST);
        __builtin_amdgcn_s_waitcnt(0);
        __atomic_signal_fence(__ATOMIC_SEQ_CST);
        AT_STORE(&f1[b], MAGIC);
    }
    float eA, eB, eC;                          // thread-exclusive prefix map
    {
        float pA = __shfl_up(rA, 1, 64), pB = __shfl_up(rB, 1, 64), pC = __shfl_up(rC, 1, 64);
        eA = (lane == 0) ? wA : pA;
        eB = (lane == 0) ? wB : pB;
        eC = (lane == 0) ? wC : pC;
    }

    // ---- fast/fallback decision (B2) ----
    int bad = (full && tid > 0 && eB < eC) ? 1 : 0;
    int cnt = __syncthreads_count(bad);
    const bool fallback = (cnt != 0) || !(k > 0.0f && k < 0.70f) || (T - gbase < 64);

    if (!fallback) {
        // ================= FAST PATH (gate-free throughput) =================
        float S = fminf(fmaxf(0.5f + eA, eB), eC);   // exact for saturated threads
        float p = 1.f, c = 0.f;
        if (full) {
#pragma unroll
            for (int j = 0; j < ITEMS; ++j) {
                float dd = d[j];
                float S1 = fmaxf(S + dd, 0.f);
                float ex = fmaxf(S1 - smax, 0.f);
                S = S1 - ex;
                float w = c + bfi * ex;
                d[j] = omb * ex + omk * w;
                c = k * w;
                p *= k;
            }
        }
#pragma unroll
        for (int s = 1; s < 64; s <<= 1) {
            float pp = __shfl_up(p, s, 64), pc = __shfl_up(c, s, 64);
            if (lane >= s) {
                float nq = p * pc + c;
                p = pp * p;
                c = nq;
            }
        }
        if (lane == 63) { sm2[wv * 2] = p; sm2[wv * 2 + 1] = c; }
        __syncthreads();   // B3
        float wP = 1.f, wQ = 0.f;
        for (int i = 0; i < wv; ++i) {
            float gp = sm2[i * 2], gq = sm2[i * 2 + 1];
            wQ = gp * wQ + gq;
            wP = wP * gp;
        }
        {
            float nq = p * wQ + c;
            p = wP * p;
            c = nq;
        }
        if (tid == TPB - 1) {                  // publish2: exact to <1e-35, gate-free
            AT_STORE(&scrP[b], p); AT_STORE(&scrQ[b], c);
            __atomic_signal_fence(__ATOMIC_SEQ_CST);
            __builtin_amdgcn_s_waitcnt(0);
            __atomic_signal_fence(__ATOMIC_SEQ_CST);
            AT_STORE(&f2[b], MAGIC);
        }
        float eP, eQ;
        {
            float pp = __shfl_up(p, 1, 64), pc = __shfl_up(c, 1, 64);
            eP = (lane == 0) ? wP : pp;
            eQ = (lane == 0) ? wQ : pc;
        }

        // speculative epilogue + store: threads >= 2, zero waits
        if (full && tid >= 2) {
            float Bst = eP * 1.0f + eQ;        // guess B_blockstart=1; err <= k^64
            float f = omk * Bst;
#pragma unroll
            for (int j = 0; j < ITEMS; ++j) { d[j] += f; f *= k; }
            float4* o4 = (float4*)out + ((long)(gbase + toff) >> 2);
#pragma unroll
            for (int u = 0; u < 8; ++u)
                o4[u] = make_float4(d[4 * u], d[4 * u + 1], d[4 * u + 2], d[4 * u + 3]);
        }

        // lane-0 fix-up: both 1-hop gates + exact serial recompute of [0,64)
        if (tid == 0) {
            float Sst;
            if (b == 0) Sst = 0.5f;
            else {
                float aA = 0.f, aB = -INF, aC = INF;
                int j = b - 1;
                for (;;) {
                    if (j < 0) { Sst = fminf(fmaxf(0.5f + aA, aB), aC); break; }
                    while (AT_LOAD(&f1[j]) != MAGIC) __builtin_amdgcn_s_sleep(1);
                    __atomic_signal_fence(__ATOMIC_ACQUIRE);
                    float Aj = AT_LOAD(&scrA[j]), Bj = AT_LOAD(&scrB[j]), Cj = AT_LOAD(&scrC[j]);
                    float nA = Aj + aA, nB = fmaxf(Bj + aA, aB), nC = fminf(fmaxf(Cj + aA, aB), aC);
                    aA = nA; aB = nB; aC = nC;
                    if (aB >= aC) { Sst = aC; break; }
                    --j;
                }
            }
            float Bcur;
            if (b == 0) Bcur = 1.0f;
            else {
                float accP = 1.f, Bacc = 0.f;
                int j = b - 1;
                for (;;) {
                    if (j < 0) { Bacc += accP * 1.0f; break; }
                    if (accP < 1e-35f) break;
                    while (AT_LOAD(&f2[j]) != MAGIC) __builtin_amdgcn_s_sleep(1);
                    __atomic_signal_fence(__ATOMIC_ACQUIRE);
                    float Pj = AT_LOAD(&scrP[j]), Qj = AT_LOAD(&scrQ[j]);
                    Bacc += accP * Qj;
                    accP *= Pj;
                    --j;
                }
                Bcur = Bacc;
            }
            // exact recompute of elements [gbase, gbase+64)
            const float4* xf = (const float4*)x + ((long)gbase >> 1);
            float Sc = Sst;
#pragma unroll
            for (int base = 0; base < 64; base += 16) {
                float4 vv[8];
#pragma unroll
                for (int u = 0; u < 8; ++u) vv[u] = xf[(base >> 1) + u];
                float o[16];
#pragma unroll
                for (int j = 0; j < 16; ++j) {
                    float dd = (j & 1) ? (vv[j >> 1].z - vv[j >> 1].w)
                                       : (vv[j >> 1].x - vv[j >> 1].y);
                    float S1 = fmaxf(Sc + dd, 0.f);
                    float ex = fmaxf(S1 - smax, 0.f);
                    Sc = S1 - ex;
                    Bcur += bfi * ex;
                    float bf = omk * Bcur;
                    Bcur -= bf;
                    o[j] = omb * ex + bf;
                }
                float4* o4 = (float4*)out + ((long)(gbase + base) >> 2);
#pragma unroll
                for (int u = 0; u < 4; ++u)
                    o4[u] = make_float4(o[4 * u], o[4 * u + 1], o[4 * u + 2], o[4 * u + 3]);
            }
        }
    } else {
        // ================= FALLBACK (exact R9 path) =================
        if (tid == 0) {
            float aA = 0.f, aB = -INF, aC = INF;
            float Sst;
            int j = b - 1;
            for (;;) {
                if (j < 0) { Sst = fminf(fmaxf(0.5f + aA, aB), aC); break; }
                while (AT_LOAD(&f1[j]) != MAGIC) __builtin_amdgcn_s_sleep(1);
                __atomic_signal_fence(__ATOMIC_ACQUIRE);
                float Aj = AT_LOAD(&scrA[j]), Bj = AT_LOAD(&scrB[j]), Cj = AT_LOAD(&scrC[j]);
                float nA = Aj + aA, nB = fmaxf(Bj + aA, aB), nC = fminf(fmaxf(Cj + aA, aB), aC);
                aA = nA; aB = nB; aC = nC;
                if (aB >= aC) { Sst = aC; break; }
                --j;
            }
            bc[0] = Sst;
        }
        __syncthreads();
        float S = fminf(fmaxf(bc[0] + eA, eB), eC);
        float p = 1.f, c = 0.f;
        if (full) {
#pragma unroll
            for (int j = 0; j < ITEMS; ++j) {
                float dd = d[j];
                float S1 = fmaxf(S + dd, 0.f);
                float ex = fmaxf(S1 - smax, 0.f);
                S = S1 - ex;
                float w = c + bfi * ex;
                d[j] = omb * ex + omk * w;
                c = k * w;
                p *= k;
            }
        }
#pragma unroll
        for (int s = 1; s < 64; s <<= 1) {
            float pp = __shfl_up(p, s, 64), pc = __shfl_up(c, s, 64);
            if (lane >= s) {
                float nq = p * pc + c;
                p = pp * p;
                c = nq;
            }
        }
        if (lane == 63) { sm2[wv * 2] = p; sm2[wv * 2 + 1] = c; }
        __syncthreads();
        float wP = 1.f, wQ = 0.f;
        for (int i = 0; i < wv; ++i) {
            float gp = sm2[i * 2], gq = sm2[i * 2 + 1];
            wQ = gp * wQ + gq;
            wP = wP * gp;
        }
        {
            float nq = p * wQ + c;
            p = wP * p;
            c = nq;
        }
        if (tid == TPB - 1) {
            AT_STORE(&scrP[b], p); AT_STORE(&scrQ[b], c);
            __atomic_signal_fence(__ATOMIC_SEQ_CST);
            __builtin_amdgcn_s_waitcnt(0);
            __atomic_signal_fence(__ATOMIC_SEQ_CST);
            AT_STORE(&f2[b], MAGIC);
        }
        float eP, eQ;
        {
            float pp = __shfl_up(p, 1, 64), pc = __shfl_up(c, 1, 64);
            eP = (lane == 0) ? wP : pp;
            eQ = (lane == 0) ? wQ : pc;
        }
        if (tid == 0) {
            float accP = 1.f, Bst = 0.f;
            int j = b - 1;
            for (;;) {
                if (j < 0) { Bst += accP * 1.0f; break; }
                if (accP < 1e-35f) break;
                while (AT_LOAD(&f2[j]) != MAGIC) __builtin_amdgcn_s_sleep(1);
                __atomic_signal_fence(__ATOMIC_ACQUIRE);
                float Pj = AT_LOAD(&scrP[j]), Qj = AT_LOAD(&scrQ[j]);
                Bst  += accP * Qj;
                accP *= Pj;
                --j;
            }
            bc[1] = Bst;
        }
        __syncthreads();
        float Bst = eP * bc[1] + eQ;
        if (full) {
            float f = omk * Bst;
#pragma unroll
            for (int j = 0; j < ITEMS; ++j) { d[j] += f; f *= k; }
            float4* o4 = (float4*)out + ((long)(gbase + toff) >> 2);
#pragma unroll
            for (int u = 0; u < 8; ++u)
                o4[u] = make_float4(d[4 * u], d[4 * u + 1], d[4 * u + 2], d[4 * u + 3]);
        }
    }
}

extern "C" void kernel_launch(void* const* d_in, const int* in_sizes, int n_in,
                              void* d_out, int out_size, void* d_ws, size_t ws_size,
                              hipStream_t stream) {
    const float* x    = (const float*)d_in[0];
    const float* BFI  = (const float*)d_in[1];
    const float* K    = (const float*)d_in[2];
    const float* Smax = (const float*)d_in[3];
    float* out = (float*)d_out;
    float* ws  = (float*)d_ws;   // ~27.4 KB; 0xAA poison = "not ready" for flags
    int T = out_size;            // 8,000,000

    awbm_kernel<<<dim3(GRID), dim3(TPB), 0, stream>>>(x, BFI, K, Smax, out, ws, T);
}